// Round 9
// baseline (1249.732 us; speedup 1.0000x reference)
//
#include <hip/hip_runtime.h>
#include <math.h>

#define NEG_SLOPE 0.2f

typedef __bf16 bf16x8 __attribute__((ext_vector_type(8)));
typedef float f32x4 __attribute__((ext_vector_type(4)));

// f32 -> bf16 bits, round-to-nearest-even
__device__ __forceinline__ ushort f2bf(float x) {
  union { float f; unsigned u; } v; v.f = x;
  unsigned r = v.u + 0x7fffu + ((v.u >> 16) & 1u);
  return (ushort)(r >> 16);
}
__device__ __forceinline__ float bf2f(ushort b) {
  union { unsigned u; float f; } v; v.u = (unsigned)b << 16;
  return v.f;
}

// LDS swizzle for [32][512B] rows (f-tile)
__device__ __forceinline__ int swz(int m) {
  return ((m & 7) << 4) | (((m >> 3) & 3) << 7);
}

// atomic float max via int/uint trick (works for mixed signs, init -inf)
__device__ __forceinline__ void atomicMaxF32(float* addr, float val) {
  if (val >= 0.f) {
    atomicMax((int*)addr, __float_as_int(val));
  } else {
    atomicMin((unsigned int*)addr, __float_as_uint(val));
  }
}

// ---------------- K0: init emax=-inf, asum=0, agg=0 ----------------
__global__ void k_init(float* __restrict__ emax, float* __restrict__ asum,
                       float* __restrict__ agg, int n) {
  int i = blockIdx.x * 256 + threadIdx.x;
  if (i < n * 4) { emax[i] = -INFINITY; asum[i] = 0.f; }
  if (i < n * 64) agg[i] = 0.f;
}

// ---------------- K prep: build concatenated bf16 weights ----------------
__global__ void k_prep(const float* __restrict__ Wfij,
                       const float* __restrict__ Wni,
                       const float* __restrict__ Wnj,
                       const float* __restrict__ Wpe,
                       ushort* __restrict__ WcatT, ushort* __restrict__ WpeT) {
  int i = blockIdx.x * 256 + threadIdx.x;
  if (i < 49152) {
    int c = i / 192, k = i % 192;
    float v = (k < 64) ? Wfij[k * 256 + c]
            : (k < 128) ? Wni[(k - 64) * 256 + c]
                        : Wnj[(k - 128) * 256 + c];
    WcatT[c * 192 + k] = f2bf(v);
  }
  if (i < 16384) {
    int k2 = i >> 6, n2 = i & 63;  // Wpe[k2][n2]
    WpeT[n2 * 256 + k2] = f2bf(Wpe[i]);
  }
}

// ---------------- K1: node transforms: hE_bf(bf16), hq(bf16) ----------------
__global__ __launch_bounds__(256) void k_node(
    const float* __restrict__ hE,
    const float* __restrict__ Wnode, const float* __restrict__ bnode,
    const float* __restrict__ Wpn,
    ushort* __restrict__ hE_bf, ushort* __restrict__ hq, int n) {
  __shared__ float hEt[64 * 36];    // transposed [k][m], stride 36 (pad)
  __shared__ float hpl[32 * 260];   // hp tile [m][c], stride 260 (pad)
  const int tid = threadIdx.x;
  const int n0 = blockIdx.x * 32;

#pragma unroll
  for (int i = 0; i < 8; ++i) {
    int flat = tid + i * 256;
    int m = flat >> 6, k = flat & 63;
    float v = (n0 + m < n) ? hE[(size_t)(n0 + m) * 64 + k] : 0.f;
    hEt[k * 36 + m] = v;
    if (n0 + m < n) hE_bf[(size_t)(n0 + m) * 64 + k] = f2bf(v);
  }
  __syncthreads();

  const int tm = tid >> 5, tc = tid & 31, c0 = tc * 8;

  // hp pass
  {
    float acc[4][8];
#pragma unroll
    for (int mm = 0; mm < 4; ++mm)
#pragma unroll
      for (int j = 0; j < 8; ++j) acc[mm][j] = 0.f;

    for (int k = 0; k < 64; ++k) {
      float4 h4 = *(const float4*)&hEt[k * 36 + tm * 4];
      float4 w0 = *(const float4*)&Wnode[k * 256 + c0];
      float4 w1 = *(const float4*)&Wnode[k * 256 + c0 + 4];
      float hv[4] = {h4.x, h4.y, h4.z, h4.w};
      float wv[8] = {w0.x, w0.y, w0.z, w0.w, w1.x, w1.y, w1.z, w1.w};
#pragma unroll
      for (int mm = 0; mm < 4; ++mm)
#pragma unroll
        for (int j = 0; j < 8; ++j) acc[mm][j] += hv[mm] * wv[j];
    }
#pragma unroll
    for (int mm = 0; mm < 4; ++mm) {
      int m = tm * 4 + mm;
#pragma unroll
      for (int j = 0; j < 8; ++j)
        hpl[m * 260 + c0 + j] = acc[mm][j] + bnode[c0 + j];
    }
  }
  __syncthreads();

  // hq pass: per-head 64x64 projection. col c0+j lives in head hh.
  const int hh = tc >> 3, dc0 = (tc & 7) * 8;
  float acc[4][8];
#pragma unroll
  for (int mm = 0; mm < 4; ++mm)
#pragma unroll
    for (int j = 0; j < 8; ++j) acc[mm][j] = 0.f;

  for (int k = 0; k < 64; ++k) {
    float4 w0 = *(const float4*)&Wpn[(size_t)(hh * 64 + k) * 64 + dc0];
    float4 w1 = *(const float4*)&Wpn[(size_t)(hh * 64 + k) * 64 + dc0 + 4];
    float wv[8] = {w0.x, w0.y, w0.z, w0.w, w1.x, w1.y, w1.z, w1.w};
#pragma unroll
    for (int mm = 0; mm < 4; ++mm) {
      float hv = hpl[(tm * 4 + mm) * 260 + hh * 64 + k];
#pragma unroll
      for (int j = 0; j < 8; ++j) acc[mm][j] += hv * wv[j];
    }
  }
#pragma unroll
  for (int mm = 0; mm < 4; ++mm) {
    int m = tm * 4 + mm;
    if (n0 + m < n) {
      ushort u[8];
#pragma unroll
      for (int j = 0; j < 8; ++j) u[j] = f2bf(acc[mm][j]);
      *(uint4*)&hq[(size_t)(n0 + m) * 256 + c0] = *(const uint4*)u;
    }
  }
}

// ---------------- K2: edge kernel — ABLATION TEMPLATE ----------------
// V=1: stage+barriers only. V=2: +GEMM1+update(atomic/e_ws/f-write).
// V=3: +GEMM2 (no stores). V=4: full (== r8 kernel).
// All phases are idempotent (e_ws/atomicMax/out1 reproduce identical values),
// so running V1..V4 back-to-back on the real buffers is safe. Weight hoist is
// kept live in all variants via a sink consumed under a data-dependent-false
// branch, so VGPR/occupancy match across variants (check VGPR_Count).
template <int V>
__global__ __launch_bounds__(256, 2) void k_edge_t(
    const float* __restrict__ hH,
    const int* __restrict__ src, const int* __restrict__ dst,
    const ushort* __restrict__ WcatT,  // [256][192] bf16
    const float* __restrict__ attn,
    const ushort* __restrict__ WpeT,   // [64][256] bf16
    const float* __restrict__ bpe,
    const ushort* __restrict__ hE_bf,  // [n][64] bf16
    float* __restrict__ e_ws, float* __restrict__ emax,
    float* __restrict__ out1, int ntiles) {
  __shared__ __align__(16) char smem[32 * 384 + 32 * 512];  // 28672B
  char* ab = smem;            // A-tile [32][384B]
  char* fb = smem + 12288;    // f-tile [32][512B]

  const int tid = threadIdx.x;
  const int w = tid >> 6, l = tid & 63;
  const int lr = l & 15, lk = l >> 4;
  const int swa = (lr & 7) << 4;
  const int stm = tid >> 3, sts = tid & 7;  // staging role: 8 thr/edge

  // ---- one-time: hoist all weights for this wave into registers
  bf16x8 bw1[6][4];
#pragma unroll
  for (int ks = 0; ks < 6; ++ks)
#pragma unroll
    for (int nt = 0; nt < 4; ++nt)
      bw1[ks][nt] = *(const bf16x8*)(WcatT +
          (size_t)(w * 64 + nt * 16 + lr) * 192 + ks * 32 + lk * 8);
  bf16x8 bw2[8];
#pragma unroll
  for (int ks = 0; ks < 8; ++ks)
    bw2[ks] = *(const bf16x8*)(WpeT +
        (size_t)(w * 16 + lr) * 256 + ks * 32 + lk * 8);
  float av[4];
#pragma unroll
  for (int nt = 0; nt < 4; ++nt) av[nt] = attn[w * 64 + nt * 16 + lr];
  const float bpv = bpe[w * 16 + lr];
  const int sw0 = swz(lr), sw1 = swz(16 + lr);

  float sink = 0.f;  // keep-alive accumulator (never stored in practice)

  for (int tile = blockIdx.x; tile < ntiles; tile += gridDim.x) {
    const int e0 = tile * 32;

    // ---- Phase 0: stage A-tile = [hH | hE_src | hE_dst] as bf16
    {
      int sn = src[e0 + stm], dn = dst[e0 + stm];
      char* arow = ab + stm * 384;
      int swm = (stm & 7) << 4;
      const float* p = hH + (size_t)(e0 + stm) * 64 + sts * 8;
      float4 x = *(const float4*)p;
      float4 y = *(const float4*)(p + 4);
      ushort u[8] = {f2bf(x.x), f2bf(x.y), f2bf(x.z), f2bf(x.w),
                     f2bf(y.x), f2bf(y.y), f2bf(y.z), f2bf(y.w)};
      *(uint4*)(arow + ((sts * 16) ^ swm)) = *(const uint4*)u;
      *(uint4*)(arow + (128 + ((sts * 16) ^ swm))) =
          *(const uint4*)(hE_bf + (size_t)sn * 64 + sts * 8);
      *(uint4*)(arow + (256 + ((sts * 16) ^ swm))) =
          *(const uint4*)(hE_bf + (size_t)dn * 64 + sts * 8);
    }
    __syncthreads();

    if constexpr (V == 1) {
      // consume A-tile so stage ds_writes/loads aren't DCE'd
      sink += *(const float*)(ab + ((tid * 16) & 12272));
    }

    f32x4 acc[2][4];
    if constexpr (V >= 2) {
      // ---- GEMM1: f_pre = A(32x192) @ Wcat(192x256)
#pragma unroll
      for (int mt = 0; mt < 2; ++mt)
#pragma unroll
        for (int nt = 0; nt < 4; ++nt) acc[mt][nt] = (f32x4){0.f, 0.f, 0.f, 0.f};

#pragma unroll
      for (int ks = 0; ks < 6; ++ks) {
        int sec = (ks >> 1) << 7;               // 128B section base
        int off = ((ks & 1) << 6) | (lk << 4);  // 0..127 within section
        bf16x8 a0 = *(const bf16x8*)(ab + lr * 384 + sec + (off ^ swa));
        bf16x8 a1 = *(const bf16x8*)(ab + (16 + lr) * 384 + sec + (off ^ swa));
#pragma unroll
        for (int nt = 0; nt < 4; ++nt) {
          acc[0][nt] = __builtin_amdgcn_mfma_f32_16x16x32_bf16(
              a0, bw1[ks][nt], acc[0][nt], 0, 0, 0);
          acc[1][nt] = __builtin_amdgcn_mfma_f32_16x16x32_bf16(
              a1, bw1[ks][nt], acc[1][nt], 0, 0, 0);
        }
      }

      // ---- leaky, logits, f -> bf16 f-tile, e_ws + atomicMax
#pragma unroll
      for (int mt = 0; mt < 2; ++mt) {
#pragma unroll
        for (int r = 0; r < 4; ++r) {
          int m = mt * 16 + lk * 4 + r;
          char* rowp = fb + m * 512;
          int sw = swz(m);
          float p = 0.f;
#pragma unroll
          for (int nt = 0; nt < 4; ++nt) {
            int c = w * 64 + nt * 16 + lr;
            float v = acc[mt][nt][r];
            v = (v >= 0.f) ? v : NEG_SLOPE * v;
            p += v * av[nt];
            *(ushort*)(rowp + ((c * 2) ^ sw)) = f2bf(v);
          }
          p += __shfl_xor(p, 1);
          p += __shfl_xor(p, 2);
          p += __shfl_xor(p, 4);
          p += __shfl_xor(p, 8);
          if (lr == 0) {
            e_ws[(size_t)(e0 + m) * 4 + w] = p;
            atomicMaxF32(&emax[(size_t)dst[e0 + m] * 4 + w], p);
          }
        }
      }
    }
    __syncthreads();

    if constexpr (V == 2) {
      // consume f-tile so its writes aren't DCE'd
      sink += *(const float*)(fb + ((tid * 16) & 16368));
    }

    if constexpr (V >= 3) {
      // ---- GEMM2: out1 = f @ Wpe; wave w owns cols [w*16,(w+1)*16)
      f32x4 acc2[2];
      acc2[0] = (f32x4){0.f, 0.f, 0.f, 0.f};
      acc2[1] = (f32x4){0.f, 0.f, 0.f, 0.f};
#pragma unroll
      for (int ks = 0; ks < 8; ++ks) {
        int ko = (ks * 32 + lk * 8) * 2;
        bf16x8 a0 = *(const bf16x8*)(fb + lr * 512 + (ko ^ sw0));
        bf16x8 a1 = *(const bf16x8*)(fb + (16 + lr) * 512 + (ko ^ sw1));
        acc2[0] = __builtin_amdgcn_mfma_f32_16x16x32_bf16(a0, bw2[ks], acc2[0],
                                                          0, 0, 0);
        acc2[1] = __builtin_amdgcn_mfma_f32_16x16x32_bf16(a1, bw2[ks], acc2[1],
                                                          0, 0, 0);
      }

      if constexpr (V == 4) {
        // epilogue: + hH (from A-tile, bf16) + bpe
#pragma unroll
        for (int mt = 0; mt < 2; ++mt)
#pragma unroll
          for (int r = 0; r < 4; ++r) {
            int m = mt * 16 + lk * 4 + r;
            int swm = (m & 7) << 4;
            ushort h =
                *(const ushort*)(ab + m * 384 + ((((w * 16 + lr) * 2)) ^ swm));
            size_t idx = (size_t)(e0 + m) * 64 + w * 16 + lr;
            out1[idx] = acc2[mt][r] + bf2f(h) + bpv;
          }
      } else {
        // keep GEMM2 results alive without storing
#pragma unroll
        for (int r = 0; r < 4; ++r) sink += acc2[0][r] + acc2[1][r];
      }
    }
    __syncthreads();  // protect LDS before next tile's staging
  }

  // keep-alive: weights + av/bpv + sink, under a data-dependent-false branch
  if constexpr (V != 4) {
#pragma unroll
    for (int ks = 0; ks < 6; ++ks)
#pragma unroll
      for (int nt = 0; nt < 4; ++nt)
        sink += (float)bw1[ks][nt][0];
#pragma unroll
    for (int ks = 0; ks < 8; ++ks) sink += (float)bw2[ks][0];
    sink += av[0] + av[1] + av[2] + av[3] + bpv;
    if (src[0] == -2147483647) out1[0] = sink;  // never true for valid input
  }
}

// ---------------- K3a: a = exp(e - emax[dst]); asum += a ----------------
__global__ void k3a(const float* __restrict__ e_ws, const int* __restrict__ dst,
                    const float* __restrict__ emax, float* __restrict__ a_ws,
                    float* __restrict__ asum, int E4) {
  int gid = blockIdx.x * 256 + threadIdx.x;
  if (gid >= E4) return;
  int e = gid >> 2, h = gid & 3;
  int dn = dst[e];
  float av = expf(e_ws[gid] - emax[dn * 4 + h]);
  a_ws[gid] = av;
  atomicAdd(&asum[dn * 4 + h], av);
}

// ---------------- K3b: agg[dst] += sum_h (a/asum) * hq[src,h,:] ----------------
__global__ __launch_bounds__(256) void k3b(
    const float* __restrict__ a_ws, const float* __restrict__ asum,
    const int* __restrict__ src, const int* __restrict__ dst,
    const ushort* __restrict__ hq, float* __restrict__ agg, int E) {
  int e = blockIdx.x * 4 + (threadIdx.x >> 6);
  if (e >= E) return;
  int d = threadIdx.x & 63;
  int sn = src[e], dn = dst[e];
  float w0 = a_ws[e * 4 + 0] / asum[dn * 4 + 0];
  float w1 = a_ws[e * 4 + 1] / asum[dn * 4 + 1];
  float w2 = a_ws[e * 4 + 2] / asum[dn * 4 + 2];
  float w3 = a_ws[e * 4 + 3] / asum[dn * 4 + 3];
  const ushort* hqp = hq + (size_t)sn * 256;
  float y = w0 * bf2f(hqp[d]) + w1 * bf2f(hqp[64 + d]) +
            w2 * bf2f(hqp[128 + d]) + w3 * bf2f(hqp[192 + d]);
  atomicAdd(&agg[(size_t)dn * 64 + d], y);
}

// ---------------- K4: out0 = hE + agg + bp_node ----------------
__global__ void k4(const float* __restrict__ hE, const float* __restrict__ agg,
                   const float* __restrict__ bpn, float* __restrict__ out0,
                   int ND) {
  int i = blockIdx.x * 256 + threadIdx.x;
  if (i < ND) out0[i] = hE[i] + agg[i] + bpn[i & 63];
}

extern "C" void kernel_launch(void* const* d_in, const int* in_sizes, int n_in,
                              void* d_out, int out_size, void* d_ws, size_t ws_size,
                              hipStream_t stream) {
  const float* h_E    = (const float*)d_in[0];
  const float* h_H    = (const float*)d_in[1];
  const int*   src    = (const int*)d_in[2];
  const int*   dst    = (const int*)d_in[3];
  const float* W_node = (const float*)d_in[4];
  const float* b_node = (const float*)d_in[5];
  const float* W_ni   = (const float*)d_in[6];
  const float* W_nj   = (const float*)d_in[7];
  const float* W_fij  = (const float*)d_in[8];
  const float* attn   = (const float*)d_in[9];
  const float* Wp_node= (const float*)d_in[10];
  const float* bp_node= (const float*)d_in[11];
  const float* Wp_edge= (const float*)d_in[12];
  const float* bp_edge= (const float*)d_in[13];

  const int n = in_sizes[0] / 64;   // 50000 nodes
  const int e = in_sizes[1] / 64;   // 800000 edges

  // workspace layout
  ushort* ws_hEbf = (ushort*)d_ws;                      // n*64 bf16
  ushort* ws_hq   = ws_hEbf + (size_t)n * 64;           // n*256 bf16
  float*  ws_e    = (float*)(ws_hq + (size_t)n * 256);  // e*4
  float*  ws_a    = ws_e + (size_t)e * 4;               // e*4
  float*  ws_emax = ws_a + (size_t)e * 4;               // n*4
  float*  ws_asum = ws_emax + (size_t)n * 4;            // n*4
  float*  ws_agg  = ws_asum + (size_t)n * 4;            // n*64
  ushort* ws_Wcat = (ushort*)(ws_agg + (size_t)n * 64); // 256*192 bf16
  ushort* ws_WpeT = ws_Wcat + 49152;                    // 64*256 bf16

  float* out0 = (float*)d_out;               // (n,64)
  float* out1 = out0 + (size_t)n * 64;       // (e,64)

  {
    int total = n * 64;
    k_init<<<(total + 255) / 256, 256, 0, stream>>>(ws_emax, ws_asum, ws_agg, n);
  }
  k_prep<<<192, 256, 0, stream>>>(W_fij, W_ni, W_nj, Wp_edge, ws_Wcat, ws_WpeT);
  {
    int blocks = (n + 31) / 32;
    k_node<<<blocks, 256, 0, stream>>>(h_E, W_node, b_node, Wp_node,
                                       ws_hEbf, ws_hq, n);
  }
  {
    int ntiles = e / 32;  // E=800000 divisible by 32
    // Ablation ladder: V1 (stage+barriers), V2 (+GEMM1+update),
    // V3 (+GEMM2), V4 (full — authoritative output). All idempotent.
    k_edge_t<1><<<1024, 256, 0, stream>>>(h_H, src, dst, ws_Wcat, attn,
                                          ws_WpeT, bp_edge, ws_hEbf, ws_e,
                                          ws_emax, out1, ntiles);
    k_edge_t<2><<<1024, 256, 0, stream>>>(h_H, src, dst, ws_Wcat, attn,
                                          ws_WpeT, bp_edge, ws_hEbf, ws_e,
                                          ws_emax, out1, ntiles);
    k_edge_t<3><<<1024, 256, 0, stream>>>(h_H, src, dst, ws_Wcat, attn,
                                          ws_WpeT, bp_edge, ws_hEbf, ws_e,
                                          ws_emax, out1, ntiles);
    k_edge_t<4><<<1024, 256, 0, stream>>>(h_H, src, dst, ws_Wcat, attn,
                                          ws_WpeT, bp_edge, ws_hEbf, ws_e,
                                          ws_emax, out1, ntiles);
  }
  {
    int total = e * 4;
    k3a<<<(total + 255) / 256, 256, 0, stream>>>(ws_e, dst, ws_emax, ws_a,
                                                 ws_asum, total);
  }
  {
    int blocks = (e + 3) / 4;
    k3b<<<blocks, 256, 0, stream>>>(ws_a, ws_asum, src, dst, ws_hq, ws_agg, e);
  }
  {
    int total = n * 64;
    k4<<<(total + 255) / 256, 256, 0, stream>>>(h_E, ws_agg, bp_node, out0,
                                                total);
  }
}

// Round 10
// 1222.819 us; speedup vs baseline: 1.0220x; 1.0220x over previous
//
#include <hip/hip_runtime.h>
#include <math.h>

#define NEG_SLOPE 0.2f

typedef __bf16 bf16x8 __attribute__((ext_vector_type(8)));
typedef float f32x4 __attribute__((ext_vector_type(4)));

// f32 -> bf16 bits, round-to-nearest-even
__device__ __forceinline__ ushort f2bf(float x) {
  union { float f; unsigned u; } v; v.f = x;
  unsigned r = v.u + 0x7fffu + ((v.u >> 16) & 1u);
  return (ushort)(r >> 16);
}
__device__ __forceinline__ float bf2f(ushort b) {
  union { unsigned u; float f; } v; v.u = (unsigned)b << 16;
  return v.f;
}

// LDS swizzle for [32][512B] rows (f-tile)
__device__ __forceinline__ int swz(int m) {
  return ((m & 7) << 4) | (((m >> 3) & 3) << 7);
}

// atomic float max via int/uint trick (works for mixed signs, init -inf)
__device__ __forceinline__ void atomicMaxF32(float* addr, float val) {
  if (val >= 0.f) {
    atomicMax((int*)addr, __float_as_int(val));
  } else {
    atomicMin((unsigned int*)addr, __float_as_uint(val));
  }
}

// ---------------- K0: init emax=-inf, asum=0, agg=0 ----------------
__global__ void k_init(float* __restrict__ emax, float* __restrict__ asum,
                       float* __restrict__ agg, int n) {
  int i = blockIdx.x * 256 + threadIdx.x;
  if (i < n * 4) { emax[i] = -INFINITY; asum[i] = 0.f; }
  if (i < n * 64) agg[i] = 0.f;
}

// ---------------- K prep: build concatenated bf16 weights ----------------
__global__ void k_prep(const float* __restrict__ Wfij,
                       const float* __restrict__ Wni,
                       const float* __restrict__ Wnj,
                       const float* __restrict__ Wpe,
                       ushort* __restrict__ WcatT, ushort* __restrict__ WpeT) {
  int i = blockIdx.x * 256 + threadIdx.x;
  if (i < 49152) {
    int c = i / 192, k = i % 192;
    float v = (k < 64) ? Wfij[k * 256 + c]
            : (k < 128) ? Wni[(k - 64) * 256 + c]
                        : Wnj[(k - 128) * 256 + c];
    WcatT[c * 192 + k] = f2bf(v);
  }
  if (i < 16384) {
    int k2 = i >> 6, n2 = i & 63;  // Wpe[k2][n2]
    WpeT[n2 * 256 + k2] = f2bf(Wpe[i]);
  }
}

// ---------------- K1: node transforms: hE_bf(bf16), hq(bf16) ----------------
__global__ __launch_bounds__(256) void k_node(
    const float* __restrict__ hE,
    const float* __restrict__ Wnode, const float* __restrict__ bnode,
    const float* __restrict__ Wpn,
    ushort* __restrict__ hE_bf, ushort* __restrict__ hq, int n) {
  __shared__ float hEt[64 * 36];    // transposed [k][m], stride 36 (pad)
  __shared__ float hpl[32 * 260];   // hp tile [m][c], stride 260 (pad)
  const int tid = threadIdx.x;
  const int n0 = blockIdx.x * 32;

#pragma unroll
  for (int i = 0; i < 8; ++i) {
    int flat = tid + i * 256;
    int m = flat >> 6, k = flat & 63;
    float v = (n0 + m < n) ? hE[(size_t)(n0 + m) * 64 + k] : 0.f;
    hEt[k * 36 + m] = v;
    if (n0 + m < n) hE_bf[(size_t)(n0 + m) * 64 + k] = f2bf(v);
  }
  __syncthreads();

  const int tm = tid >> 5, tc = tid & 31, c0 = tc * 8;

  // hp pass
  {
    float acc[4][8];
#pragma unroll
    for (int mm = 0; mm < 4; ++mm)
#pragma unroll
      for (int j = 0; j < 8; ++j) acc[mm][j] = 0.f;

    for (int k = 0; k < 64; ++k) {
      float4 h4 = *(const float4*)&hEt[k * 36 + tm * 4];
      float4 w0 = *(const float4*)&Wnode[k * 256 + c0];
      float4 w1 = *(const float4*)&Wnode[k * 256 + c0 + 4];
      float hv[4] = {h4.x, h4.y, h4.z, h4.w};
      float wv[8] = {w0.x, w0.y, w0.z, w0.w, w1.x, w1.y, w1.z, w1.w};
#pragma unroll
      for (int mm = 0; mm < 4; ++mm)
#pragma unroll
        for (int j = 0; j < 8; ++j) acc[mm][j] += hv[mm] * wv[j];
    }
#pragma unroll
    for (int mm = 0; mm < 4; ++mm) {
      int m = tm * 4 + mm;
#pragma unroll
      for (int j = 0; j < 8; ++j)
        hpl[m * 260 + c0 + j] = acc[mm][j] + bnode[c0 + j];
    }
  }
  __syncthreads();

  // hq pass: per-head 64x64 projection. col c0+j lives in head hh.
  const int hh = tc >> 3, dc0 = (tc & 7) * 8;
  float acc[4][8];
#pragma unroll
  for (int mm = 0; mm < 4; ++mm)
#pragma unroll
    for (int j = 0; j < 8; ++j) acc[mm][j] = 0.f;

  for (int k = 0; k < 64; ++k) {
    float4 w0 = *(const float4*)&Wpn[(size_t)(hh * 64 + k) * 64 + dc0];
    float4 w1 = *(const float4*)&Wpn[(size_t)(hh * 64 + k) * 64 + dc0 + 4];
    float wv[8] = {w0.x, w0.y, w0.z, w0.w, w1.x, w1.y, w1.z, w1.w};
#pragma unroll
    for (int mm = 0; mm < 4; ++mm) {
      float hv = hpl[(tm * 4 + mm) * 260 + hh * 64 + k];
#pragma unroll
      for (int j = 0; j < 8; ++j) acc[mm][j] += hv * wv[j];
    }
  }
#pragma unroll
  for (int mm = 0; mm < 4; ++mm) {
    int m = tm * 4 + mm;
    if (n0 + m < n) {
      ushort u[8];
#pragma unroll
      for (int j = 0; j < 8; ++j) u[j] = f2bf(acc[mm][j]);
      *(uint4*)&hq[(size_t)(n0 + m) * 256 + c0] = *(const uint4*)u;
    }
  }
}

// ---------------- K2: edge kernel (pipelined persistent, 1 barrier/tile) ----
// Double-buffered A/f tiles. Per iteration: issue next tile's staging loads +
// this tile's residual-hH loads FIRST (latency hides under GEMM1/update),
// ds_write the prefetch late, ONE barrier, then GEMM2+stores (store drain and
// atomicMax drain complete in the shadow of the next tile's front-end).
// Weights stay register-resident (r7 win). Occupancy unchanged (2 blocks/CU).
__global__ __launch_bounds__(256, 2) void k_edge(
    const float* __restrict__ hH,
    const int* __restrict__ src, const int* __restrict__ dst,
    const ushort* __restrict__ WcatT,  // [256][192] bf16
    const float* __restrict__ attn,
    const ushort* __restrict__ WpeT,   // [64][256] bf16
    const float* __restrict__ bpe,
    const ushort* __restrict__ hE_bf,  // [n][64] bf16
    float* __restrict__ e_ws, float* __restrict__ emax,
    float* __restrict__ out1, int ntiles) {
  // A0 @0, A1 @12288, F0 @24576, F1 @40960  (total 57344B)
  __shared__ __align__(16) char smem[57344];

  const int tid = threadIdx.x;
  const int w = tid >> 6, l = tid & 63;
  const int lr = l & 15, lk = l >> 4;
  const int swa = (lr & 7) << 4;
  const int stm = tid >> 3, sts = tid & 7;  // staging role: 8 thr/edge
  const int swm = (stm & 7) << 4;

  // ---- one-time: hoist all weights for this wave into registers
  bf16x8 bw1[6][4];
#pragma unroll
  for (int ks = 0; ks < 6; ++ks)
#pragma unroll
    for (int nt = 0; nt < 4; ++nt)
      bw1[ks][nt] = *(const bf16x8*)(WcatT +
          (size_t)(w * 64 + nt * 16 + lr) * 192 + ks * 32 + lk * 8);
  bf16x8 bw2[8];
#pragma unroll
  for (int ks = 0; ks < 8; ++ks)
    bw2[ks] = *(const bf16x8*)(WpeT +
        (size_t)(w * 16 + lr) * 256 + ks * 32 + lk * 8);
  float av[4];
#pragma unroll
  for (int nt = 0; nt < 4; ++nt) av[nt] = attn[w * 64 + nt * 16 + lr];
  const float bpv = bpe[w * 16 + lr];
  const int sw0 = swz(lr), sw1 = swz(16 + lr);

  // ---- prologue: stage first tile into A[0]
  const int tile0 = blockIdx.x;
  if (tile0 < ntiles) {
    const int e0 = tile0 * 32;
    int sn = src[e0 + stm], dn = dst[e0 + stm];
    char* arow = smem + stm * 384;
    const float* p = hH + (size_t)(e0 + stm) * 64 + sts * 8;
    float4 x = *(const float4*)p;
    float4 y = *(const float4*)(p + 4);
    ushort u[8] = {f2bf(x.x), f2bf(x.y), f2bf(x.z), f2bf(x.w),
                   f2bf(y.x), f2bf(y.y), f2bf(y.z), f2bf(y.w)};
    *(uint4*)(arow + ((sts * 16) ^ swm)) = *(const uint4*)u;
    *(uint4*)(arow + (128 + ((sts * 16) ^ swm))) =
        *(const uint4*)(hE_bf + (size_t)sn * 64 + sts * 8);
    *(uint4*)(arow + (256 + ((sts * 16) ^ swm))) =
        *(const uint4*)(hE_bf + (size_t)dn * 64 + sts * 8);
  }
  __syncthreads();

  int cur = 0;
  for (int tile = tile0; tile < ntiles; tile += gridDim.x, cur ^= 1) {
    const int e0 = tile * 32;
    char* abc = smem + cur * 12288;            // A[cur]  (GEMM1 source)
    char* abn = smem + (cur ^ 1) * 12288;      // A[1-cur] (prefetch dest)
    char* fbc = smem + 24576 + cur * 16384;    // F[cur]

    // ---- 1a: residual hH loads for CURRENT tile (consumed in epilogue)
    float rh[8];
#pragma unroll
    for (int mt = 0; mt < 2; ++mt)
#pragma unroll
      for (int r = 0; r < 4; ++r)
        rh[mt * 4 + r] =
            hH[(size_t)(e0 + mt * 16 + lk * 4 + r) * 64 + w * 16 + lr];

    // ---- 1b: issue NEXT tile's staging loads (clamped; redundant on last)
    int ntile = tile + gridDim.x;
    if (ntile >= ntiles) ntile = tile;
    const int ne0 = ntile * 32;
    const int psn = src[ne0 + stm], pdn = dst[ne0 + stm];
    const float* pp = hH + (size_t)(ne0 + stm) * 64 + sts * 8;
    float4 px = *(const float4*)pp;
    float4 py = *(const float4*)(pp + 4);
    uint4 pi = *(const uint4*)(hE_bf + (size_t)psn * 64 + sts * 8);
    uint4 pj = *(const uint4*)(hE_bf + (size_t)pdn * 64 + sts * 8);

    // ---- 2: GEMM1: f_pre = A(32x192) @ Wcat(192x256)
    f32x4 acc[2][4];
#pragma unroll
    for (int mt = 0; mt < 2; ++mt)
#pragma unroll
      for (int nt = 0; nt < 4; ++nt) acc[mt][nt] = (f32x4){0.f, 0.f, 0.f, 0.f};

#pragma unroll
    for (int ks = 0; ks < 6; ++ks) {
      int sec = (ks >> 1) << 7;               // 128B section base
      int off = ((ks & 1) << 6) | (lk << 4);  // 0..127 within section
      bf16x8 a0 = *(const bf16x8*)(abc + lr * 384 + sec + (off ^ swa));
      bf16x8 a1 = *(const bf16x8*)(abc + (16 + lr) * 384 + sec + (off ^ swa));
#pragma unroll
      for (int nt = 0; nt < 4; ++nt) {
        acc[0][nt] = __builtin_amdgcn_mfma_f32_16x16x32_bf16(
            a0, bw1[ks][nt], acc[0][nt], 0, 0, 0);
        acc[1][nt] = __builtin_amdgcn_mfma_f32_16x16x32_bf16(
            a1, bw1[ks][nt], acc[1][nt], 0, 0, 0);
      }
    }

    // ---- 3: leaky, logits, f -> bf16 f-tile, e_ws + atomicMax
#pragma unroll
    for (int mt = 0; mt < 2; ++mt) {
#pragma unroll
      for (int r = 0; r < 4; ++r) {
        int m = mt * 16 + lk * 4 + r;
        char* rowp = fbc + m * 512;
        int sw = swz(m);
        float p = 0.f;
#pragma unroll
        for (int nt = 0; nt < 4; ++nt) {
          int c = w * 64 + nt * 16 + lr;
          float v = acc[mt][nt][r];
          v = (v >= 0.f) ? v : NEG_SLOPE * v;
          p += v * av[nt];
          *(ushort*)(rowp + ((c * 2) ^ sw)) = f2bf(v);
        }
        p += __shfl_xor(p, 1);
        p += __shfl_xor(p, 2);
        p += __shfl_xor(p, 4);
        p += __shfl_xor(p, 8);
        if (lr == 0) {
          e_ws[(size_t)(e0 + m) * 4 + w] = p;
          atomicMaxF32(&emax[(size_t)dst[e0 + m] * 4 + w], p);
        }
      }
    }

    // ---- 4: write prefetched next-tile A (waits on 1b loads here)
    {
      char* arow = abn + stm * 384;
      ushort u[8] = {f2bf(px.x), f2bf(px.y), f2bf(px.z), f2bf(px.w),
                     f2bf(py.x), f2bf(py.y), f2bf(py.z), f2bf(py.w)};
      *(uint4*)(arow + ((sts * 16) ^ swm)) = *(const uint4*)u;
      *(uint4*)(arow + (128 + ((sts * 16) ^ swm))) = pi;
      *(uint4*)(arow + (256 + ((sts * 16) ^ swm))) = pj;
    }

    // ---- 5: the single barrier (publishes F[cur] and A[1-cur])
    __syncthreads();

    // ---- 6: GEMM2: out1 = f @ Wpe; wave w owns cols [w*16,(w+1)*16)
    f32x4 acc2[2];
    acc2[0] = (f32x4){0.f, 0.f, 0.f, 0.f};
    acc2[1] = (f32x4){0.f, 0.f, 0.f, 0.f};
#pragma unroll
    for (int ks = 0; ks < 8; ++ks) {
      int ko = (ks * 32 + lk * 8) * 2;
      bf16x8 a0 = *(const bf16x8*)(fbc + lr * 512 + (ko ^ sw0));
      bf16x8 a1 = *(const bf16x8*)(fbc + (16 + lr) * 512 + (ko ^ sw1));
      acc2[0] =
          __builtin_amdgcn_mfma_f32_16x16x32_bf16(a0, bw2[ks], acc2[0], 0, 0, 0);
      acc2[1] =
          __builtin_amdgcn_mfma_f32_16x16x32_bf16(a1, bw2[ks], acc2[1], 0, 0, 0);
    }

    // epilogue: + hH (f32, loaded in 1a) + bpe; stores drain after barrier
#pragma unroll
    for (int mt = 0; mt < 2; ++mt)
#pragma unroll
      for (int r = 0; r < 4; ++r) {
        int m = mt * 16 + lk * 4 + r;
        size_t idx = (size_t)(e0 + m) * 64 + w * 16 + lr;
        out1[idx] = acc2[mt][r] + rh[mt * 4 + r] + bpv;
      }
  }
}

// ---------------- K3a: a = exp(e - emax[dst]); asum += a ----------------
__global__ void k3a(const float* __restrict__ e_ws, const int* __restrict__ dst,
                    const float* __restrict__ emax, float* __restrict__ a_ws,
                    float* __restrict__ asum, int E4) {
  int gid = blockIdx.x * 256 + threadIdx.x;
  if (gid >= E4) return;
  int e = gid >> 2, h = gid & 3;
  int dn = dst[e];
  float av = expf(e_ws[gid] - emax[dn * 4 + h]);
  a_ws[gid] = av;
  atomicAdd(&asum[dn * 4 + h], av);
}

// ---------------- K3b: agg[dst] += sum_h (a/asum) * hq[src,h,:] ----------------
__global__ __launch_bounds__(256) void k3b(
    const float* __restrict__ a_ws, const float* __restrict__ asum,
    const int* __restrict__ src, const int* __restrict__ dst,
    const ushort* __restrict__ hq, float* __restrict__ agg, int E) {
  int e = blockIdx.x * 4 + (threadIdx.x >> 6);
  if (e >= E) return;
  int d = threadIdx.x & 63;
  int sn = src[e], dn = dst[e];
  float w0 = a_ws[e * 4 + 0] / asum[dn * 4 + 0];
  float w1 = a_ws[e * 4 + 1] / asum[dn * 4 + 1];
  float w2 = a_ws[e * 4 + 2] / asum[dn * 4 + 2];
  float w3 = a_ws[e * 4 + 3] / asum[dn * 4 + 3];
  const ushort* hqp = hq + (size_t)sn * 256;
  float y = w0 * bf2f(hqp[d]) + w1 * bf2f(hqp[64 + d]) +
            w2 * bf2f(hqp[128 + d]) + w3 * bf2f(hqp[192 + d]);
  atomicAdd(&agg[(size_t)dn * 64 + d], y);
}

// ---------------- K4: out0 = hE + agg + bp_node ----------------
__global__ void k4(const float* __restrict__ hE, const float* __restrict__ agg,
                   const float* __restrict__ bpn, float* __restrict__ out0,
                   int ND) {
  int i = blockIdx.x * 256 + threadIdx.x;
  if (i < ND) out0[i] = hE[i] + agg[i] + bpn[i & 63];
}

extern "C" void kernel_launch(void* const* d_in, const int* in_sizes, int n_in,
                              void* d_out, int out_size, void* d_ws, size_t ws_size,
                              hipStream_t stream) {
  const float* h_E    = (const float*)d_in[0];
  const float* h_H    = (const float*)d_in[1];
  const int*   src    = (const int*)d_in[2];
  const int*   dst    = (const int*)d_in[3];
  const float* W_node = (const float*)d_in[4];
  const float* b_node = (const float*)d_in[5];
  const float* W_ni   = (const float*)d_in[6];
  const float* W_nj   = (const float*)d_in[7];
  const float* W_fij  = (const float*)d_in[8];
  const float* attn   = (const float*)d_in[9];
  const float* Wp_node= (const float*)d_in[10];
  const float* bp_node= (const float*)d_in[11];
  const float* Wp_edge= (const float*)d_in[12];
  const float* bp_edge= (const float*)d_in[13];

  const int n = in_sizes[0] / 64;   // 50000 nodes
  const int e = in_sizes[1] / 64;   // 800000 edges

  // workspace layout
  ushort* ws_hEbf = (ushort*)d_ws;                      // n*64 bf16
  ushort* ws_hq   = ws_hEbf + (size_t)n * 64;           // n*256 bf16
  float*  ws_e    = (float*)(ws_hq + (size_t)n * 256);  // e*4
  float*  ws_a    = ws_e + (size_t)e * 4;               // e*4
  float*  ws_emax = ws_a + (size_t)e * 4;               // n*4
  float*  ws_asum = ws_emax + (size_t)n * 4;            // n*4
  float*  ws_agg  = ws_asum + (size_t)n * 4;            // n*64
  ushort* ws_Wcat = (ushort*)(ws_agg + (size_t)n * 64); // 256*192 bf16
  ushort* ws_WpeT = ws_Wcat + 49152;                    // 64*256 bf16

  float* out0 = (float*)d_out;               // (n,64)
  float* out1 = out0 + (size_t)n * 64;       // (e,64)

  {
    int total = n * 64;
    k_init<<<(total + 255) / 256, 256, 0, stream>>>(ws_emax, ws_asum, ws_agg, n);
  }
  k_prep<<<192, 256, 0, stream>>>(W_fij, W_ni, W_nj, Wp_edge, ws_Wcat, ws_WpeT);
  {
    int blocks = (n + 31) / 32;
    k_node<<<blocks, 256, 0, stream>>>(h_E, W_node, b_node, Wp_node,
                                       ws_hEbf, ws_hq, n);
  }
  {
    int ntiles = e / 32;  // E=800000 divisible by 32
    k_edge<<<512, 256, 0, stream>>>(h_H, src, dst, ws_Wcat, attn, ws_WpeT,
                                    bp_edge, ws_hEbf, ws_e, ws_emax, out1,
                                    ntiles);
  }
  {
    int total = e * 4;
    k3a<<<(total + 255) / 256, 256, 0, stream>>>(ws_e, dst, ws_emax, ws_a,
                                                 ws_asum, total);
  }
  {
    int blocks = (e + 3) / 4;
    k3b<<<blocks, 256, 0, stream>>>(ws_a, ws_asum, src, dst, ws_hq, ws_agg, e);
  }
  {
    int total = n * 64;
    k4<<<(total + 255) / 256, 256, 0, stream>>>(h_E, ws_agg, bp_node, out0,
                                                total);
  }
}

// Round 11
// 1106.018 us; speedup vs baseline: 1.1299x; 1.1056x over previous
//
#include <hip/hip_runtime.h>
#include <math.h>

#define NEG_SLOPE 0.2f

typedef __bf16 bf16x8 __attribute__((ext_vector_type(8)));
typedef float f32x4 __attribute__((ext_vector_type(4)));

// f32 -> bf16 bits, round-to-nearest-even
__device__ __forceinline__ ushort f2bf(float x) {
  union { float f; unsigned u; } v; v.f = x;
  unsigned r = v.u + 0x7fffu + ((v.u >> 16) & 1u);
  return (ushort)(r >> 16);
}
__device__ __forceinline__ float bf2f(ushort b) {
  union { unsigned u; float f; } v; v.u = (unsigned)b << 16;
  return v.f;
}

// LDS swizzle for [32][512B] rows (f-tile)
__device__ __forceinline__ int swz(int m) {
  return ((m & 7) << 4) | (((m >> 3) & 3) << 7);
}

// atomic float max via int/uint trick (works for mixed signs, init -inf)
__device__ __forceinline__ void atomicMaxF32(float* addr, float val) {
  if (val >= 0.f) {
    atomicMax((int*)addr, __float_as_int(val));
  } else {
    atomicMin((unsigned int*)addr, __float_as_uint(val));
  }
}

// ---------------- K0: init emax=-inf, asum=0, agg=0 ----------------
__global__ void k_init(float* __restrict__ emax, float* __restrict__ asum,
                       float* __restrict__ agg, int n) {
  int i = blockIdx.x * 256 + threadIdx.x;
  if (i < n * 4) { emax[i] = -INFINITY; asum[i] = 0.f; }
  if (i < n * 64) agg[i] = 0.f;
}

// ---------------- K prep: build concatenated bf16 weights ----------------
__global__ void k_prep(const float* __restrict__ Wfij,
                       const float* __restrict__ Wni,
                       const float* __restrict__ Wnj,
                       const float* __restrict__ Wpe,
                       ushort* __restrict__ WcatT, ushort* __restrict__ WpeT) {
  int i = blockIdx.x * 256 + threadIdx.x;
  if (i < 49152) {
    int c = i / 192, k = i % 192;
    float v = (k < 64) ? Wfij[k * 256 + c]
            : (k < 128) ? Wni[(k - 64) * 256 + c]
                        : Wnj[(k - 128) * 256 + c];
    WcatT[c * 192 + k] = f2bf(v);
  }
  if (i < 16384) {
    int k2 = i >> 6, n2 = i & 63;  // Wpe[k2][n2]
    WpeT[n2 * 256 + k2] = f2bf(Wpe[i]);
  }
}

// ---------------- K1: node transforms: hE_bf(bf16), hq(bf16) ----------------
__global__ __launch_bounds__(256) void k_node(
    const float* __restrict__ hE,
    const float* __restrict__ Wnode, const float* __restrict__ bnode,
    const float* __restrict__ Wpn,
    ushort* __restrict__ hE_bf, ushort* __restrict__ hq, int n) {
  __shared__ float hEt[64 * 36];    // transposed [k][m], stride 36 (pad)
  __shared__ float hpl[32 * 260];   // hp tile [m][c], stride 260 (pad)
  const int tid = threadIdx.x;
  const int n0 = blockIdx.x * 32;

#pragma unroll
  for (int i = 0; i < 8; ++i) {
    int flat = tid + i * 256;
    int m = flat >> 6, k = flat & 63;
    float v = (n0 + m < n) ? hE[(size_t)(n0 + m) * 64 + k] : 0.f;
    hEt[k * 36 + m] = v;
    if (n0 + m < n) hE_bf[(size_t)(n0 + m) * 64 + k] = f2bf(v);
  }
  __syncthreads();

  const int tm = tid >> 5, tc = tid & 31, c0 = tc * 8;

  // hp pass
  {
    float acc[4][8];
#pragma unroll
    for (int mm = 0; mm < 4; ++mm)
#pragma unroll
      for (int j = 0; j < 8; ++j) acc[mm][j] = 0.f;

    for (int k = 0; k < 64; ++k) {
      float4 h4 = *(const float4*)&hEt[k * 36 + tm * 4];
      float4 w0 = *(const float4*)&Wnode[k * 256 + c0];
      float4 w1 = *(const float4*)&Wnode[k * 256 + c0 + 4];
      float hv[4] = {h4.x, h4.y, h4.z, h4.w};
      float wv[8] = {w0.x, w0.y, w0.z, w0.w, w1.x, w1.y, w1.z, w1.w};
#pragma unroll
      for (int mm = 0; mm < 4; ++mm)
#pragma unroll
        for (int j = 0; j < 8; ++j) acc[mm][j] += hv[mm] * wv[j];
    }
#pragma unroll
    for (int mm = 0; mm < 4; ++mm) {
      int m = tm * 4 + mm;
#pragma unroll
      for (int j = 0; j < 8; ++j)
        hpl[m * 260 + c0 + j] = acc[mm][j] + bnode[c0 + j];
    }
  }
  __syncthreads();

  // hq pass: per-head 64x64 projection. col c0+j lives in head hh.
  const int hh = tc >> 3, dc0 = (tc & 7) * 8;
  float acc[4][8];
#pragma unroll
  for (int mm = 0; mm < 4; ++mm)
#pragma unroll
    for (int j = 0; j < 8; ++j) acc[mm][j] = 0.f;

  for (int k = 0; k < 64; ++k) {
    float4 w0 = *(const float4*)&Wpn[(size_t)(hh * 64 + k) * 64 + dc0];
    float4 w1 = *(const float4*)&Wpn[(size_t)(hh * 64 + k) * 64 + dc0 + 4];
    float wv[8] = {w0.x, w0.y, w0.z, w0.w, w1.x, w1.y, w1.z, w1.w};
#pragma unroll
    for (int mm = 0; mm < 4; ++mm) {
      float hv = hpl[(tm * 4 + mm) * 260 + hh * 64 + k];
#pragma unroll
      for (int j = 0; j < 8; ++j) acc[mm][j] += hv * wv[j];
    }
  }
#pragma unroll
  for (int mm = 0; mm < 4; ++mm) {
    int m = tm * 4 + mm;
    if (n0 + m < n) {
      ushort u[8];
#pragma unroll
      for (int j = 0; j < 8; ++j) u[j] = f2bf(acc[mm][j]);
      *(uint4*)&hq[(size_t)(n0 + m) * 256 + c0] = *(const uint4*)u;
    }
  }
}

// ---------------- K2: edge kernel (pipelined persistent, 1 barrier/tile,
//                      NO extra hH stream — residual from A-tile) ----------
// vs r10: the f32 residual re-read of hH (which tipped the L3 over capacity,
// FETCH 190MB->1.13GB) is deleted. Residual comes from the A-tile again (as in
// r8), read into registers at phase 3.5 BEFORE the barrier. Race analysis:
//   A[cur] is written by iter t+1 phase 4 (fast wave). Phase 3.5 reads of
//   iter t happen before iter t's phase-5 barrier; any wave in iter t+1 has
//   passed that barrier, hence all waves completed phase 3.5. Safe.
//   F[cur] read (phase 6, iter t) vs next write (phase 3, iter t+2): every
//   wave must pass iter t+1's barrier first, which requires finishing iter t
//   phase 6. Safe. A[cur^1] write (phase 4, iter t) vs read (phase 2, iter
//   t+1): separated by iter t's barrier. Safe.
__global__ __launch_bounds__(256, 2) void k_edge(
    const float* __restrict__ hH,
    const int* __restrict__ src, const int* __restrict__ dst,
    const ushort* __restrict__ WcatT,  // [256][192] bf16
    const float* __restrict__ attn,
    const ushort* __restrict__ WpeT,   // [64][256] bf16
    const float* __restrict__ bpe,
    const ushort* __restrict__ hE_bf,  // [n][64] bf16
    float* __restrict__ e_ws, float* __restrict__ emax,
    float* __restrict__ out1, int ntiles) {
  // A0 @0, A1 @12288, F0 @24576, F1 @40960  (total 57344B)
  __shared__ __align__(16) char smem[57344];

  const int tid = threadIdx.x;
  const int w = tid >> 6, l = tid & 63;
  const int lr = l & 15, lk = l >> 4;
  const int swa = (lr & 7) << 4;
  const int stm = tid >> 3, sts = tid & 7;  // staging role: 8 thr/edge
  const int swm = (stm & 7) << 4;

  // ---- one-time: hoist all weights for this wave into registers
  bf16x8 bw1[6][4];
#pragma unroll
  for (int ks = 0; ks < 6; ++ks)
#pragma unroll
    for (int nt = 0; nt < 4; ++nt)
      bw1[ks][nt] = *(const bf16x8*)(WcatT +
          (size_t)(w * 64 + nt * 16 + lr) * 192 + ks * 32 + lk * 8);
  bf16x8 bw2[8];
#pragma unroll
  for (int ks = 0; ks < 8; ++ks)
    bw2[ks] = *(const bf16x8*)(WpeT +
        (size_t)(w * 16 + lr) * 256 + ks * 32 + lk * 8);
  float av[4];
#pragma unroll
  for (int nt = 0; nt < 4; ++nt) av[nt] = attn[w * 64 + nt * 16 + lr];
  const float bpv = bpe[w * 16 + lr];
  const int sw0 = swz(lr), sw1 = swz(16 + lr);

  // ---- prologue: stage first tile into A[0]
  const int tile0 = blockIdx.x;
  if (tile0 < ntiles) {
    const int e0 = tile0 * 32;
    int sn = src[e0 + stm], dn = dst[e0 + stm];
    char* arow = smem + stm * 384;
    const float* p = hH + (size_t)(e0 + stm) * 64 + sts * 8;
    float4 x = *(const float4*)p;
    float4 y = *(const float4*)(p + 4);
    ushort u[8] = {f2bf(x.x), f2bf(x.y), f2bf(x.z), f2bf(x.w),
                   f2bf(y.x), f2bf(y.y), f2bf(y.z), f2bf(y.w)};
    *(uint4*)(arow + ((sts * 16) ^ swm)) = *(const uint4*)u;
    *(uint4*)(arow + (128 + ((sts * 16) ^ swm))) =
        *(const uint4*)(hE_bf + (size_t)sn * 64 + sts * 8);
    *(uint4*)(arow + (256 + ((sts * 16) ^ swm))) =
        *(const uint4*)(hE_bf + (size_t)dn * 64 + sts * 8);
  }
  __syncthreads();

  int cur = 0;
  for (int tile = tile0; tile < ntiles; tile += gridDim.x, cur ^= 1) {
    const int e0 = tile * 32;
    char* abc = smem + cur * 12288;            // A[cur]  (GEMM1 source)
    char* abn = smem + (cur ^ 1) * 12288;      // A[1-cur] (prefetch dest)
    char* fbc = smem + 24576 + cur * 16384;    // F[cur]

    // ---- 1: issue NEXT tile's staging loads (latency hidden under compute)
    int ntile = tile + gridDim.x;
    if (ntile >= ntiles) ntile = tile;
    const int ne0 = ntile * 32;
    const int psn = src[ne0 + stm], pdn = dst[ne0 + stm];
    const float* pp = hH + (size_t)(ne0 + stm) * 64 + sts * 8;
    float4 px = *(const float4*)pp;
    float4 py = *(const float4*)(pp + 4);
    uint4 pi = *(const uint4*)(hE_bf + (size_t)psn * 64 + sts * 8);
    uint4 pj = *(const uint4*)(hE_bf + (size_t)pdn * 64 + sts * 8);

    // ---- 2: GEMM1: f_pre = A(32x192) @ Wcat(192x256)
    f32x4 acc[2][4];
#pragma unroll
    for (int mt = 0; mt < 2; ++mt)
#pragma unroll
      for (int nt = 0; nt < 4; ++nt) acc[mt][nt] = (f32x4){0.f, 0.f, 0.f, 0.f};

#pragma unroll
    for (int ks = 0; ks < 6; ++ks) {
      int sec = (ks >> 1) << 7;               // 128B section base
      int off = ((ks & 1) << 6) | (lk << 4);  // 0..127 within section
      bf16x8 a0 = *(const bf16x8*)(abc + lr * 384 + sec + (off ^ swa));
      bf16x8 a1 = *(const bf16x8*)(abc + (16 + lr) * 384 + sec + (off ^ swa));
#pragma unroll
      for (int nt = 0; nt < 4; ++nt) {
        acc[0][nt] = __builtin_amdgcn_mfma_f32_16x16x32_bf16(
            a0, bw1[ks][nt], acc[0][nt], 0, 0, 0);
        acc[1][nt] = __builtin_amdgcn_mfma_f32_16x16x32_bf16(
            a1, bw1[ks][nt], acc[1][nt], 0, 0, 0);
      }
    }

    // ---- 3: leaky, logits, f -> bf16 f-tile, e_ws + atomicMax
#pragma unroll
    for (int mt = 0; mt < 2; ++mt) {
#pragma unroll
      for (int r = 0; r < 4; ++r) {
        int m = mt * 16 + lk * 4 + r;
        char* rowp = fbc + m * 512;
        int sw = swz(m);
        float p = 0.f;
#pragma unroll
        for (int nt = 0; nt < 4; ++nt) {
          int c = w * 64 + nt * 16 + lr;
          float v = acc[mt][nt][r];
          v = (v >= 0.f) ? v : NEG_SLOPE * v;
          p += v * av[nt];
          *(ushort*)(rowp + ((c * 2) ^ sw)) = f2bf(v);
        }
        p += __shfl_xor(p, 1);
        p += __shfl_xor(p, 2);
        p += __shfl_xor(p, 4);
        p += __shfl_xor(p, 8);
        if (lr == 0) {
          e_ws[(size_t)(e0 + m) * 4 + w] = p;
          atomicMaxF32(&emax[(size_t)dst[e0 + m] * 4 + w], p);
        }
      }
    }

    // ---- 3.5: residual hH (bf16) from A[cur] -> regs, BEFORE the barrier
    float rh[8];
#pragma unroll
    for (int mt = 0; mt < 2; ++mt)
#pragma unroll
      for (int r = 0; r < 4; ++r) {
        int m = mt * 16 + lk * 4 + r;
        int swmr = (m & 7) << 4;
        rh[mt * 4 + r] = bf2f(*(const ushort*)(
            abc + m * 384 + ((((w * 16 + lr) * 2)) ^ swmr)));
      }

    // ---- 4: write prefetched next-tile A (waits on phase-1 loads here)
    {
      char* arow = abn + stm * 384;
      ushort u[8] = {f2bf(px.x), f2bf(px.y), f2bf(px.z), f2bf(px.w),
                     f2bf(py.x), f2bf(py.y), f2bf(py.z), f2bf(py.w)};
      *(uint4*)(arow + ((sts * 16) ^ swm)) = *(const uint4*)u;
      *(uint4*)(arow + (128 + ((sts * 16) ^ swm))) = pi;
      *(uint4*)(arow + (256 + ((sts * 16) ^ swm))) = pj;
    }

    // ---- 5: the single barrier (publishes F[cur] and A[1-cur])
    __syncthreads();

    // ---- 6: GEMM2: out1 = f @ Wpe; wave w owns cols [w*16,(w+1)*16)
    f32x4 acc2[2];
    acc2[0] = (f32x4){0.f, 0.f, 0.f, 0.f};
    acc2[1] = (f32x4){0.f, 0.f, 0.f, 0.f};
#pragma unroll
    for (int ks = 0; ks < 8; ++ks) {
      int ko = (ks * 32 + lk * 8) * 2;
      bf16x8 a0 = *(const bf16x8*)(fbc + lr * 512 + (ko ^ sw0));
      bf16x8 a1 = *(const bf16x8*)(fbc + (16 + lr) * 512 + (ko ^ sw1));
      acc2[0] =
          __builtin_amdgcn_mfma_f32_16x16x32_bf16(a0, bw2[ks], acc2[0], 0, 0, 0);
      acc2[1] =
          __builtin_amdgcn_mfma_f32_16x16x32_bf16(a1, bw2[ks], acc2[1], 0, 0, 0);
    }

    // epilogue: + hH (bf16 residual from phase 3.5) + bpe
#pragma unroll
    for (int mt = 0; mt < 2; ++mt)
#pragma unroll
      for (int r = 0; r < 4; ++r) {
        int m = mt * 16 + lk * 4 + r;
        size_t idx = (size_t)(e0 + m) * 64 + w * 16 + lr;
        out1[idx] = acc2[mt][r] + rh[mt * 4 + r] + bpv;
      }
  }
}

// ---------------- K3a: a = exp(e - emax[dst]); asum += a ----------------
__global__ void k3a(const float* __restrict__ e_ws, const int* __restrict__ dst,
                    const float* __restrict__ emax, float* __restrict__ a_ws,
                    float* __restrict__ asum, int E4) {
  int gid = blockIdx.x * 256 + threadIdx.x;
  if (gid >= E4) return;
  int e = gid >> 2, h = gid & 3;
  int dn = dst[e];
  float av = expf(e_ws[gid] - emax[dn * 4 + h]);
  a_ws[gid] = av;
  atomicAdd(&asum[dn * 4 + h], av);
}

// ---------------- K3b: agg[dst] += sum_h (a/asum) * hq[src,h,:] ----------------
__global__ __launch_bounds__(256) void k3b(
    const float* __restrict__ a_ws, const float* __restrict__ asum,
    const int* __restrict__ src, const int* __restrict__ dst,
    const ushort* __restrict__ hq, float* __restrict__ agg, int E) {
  int e = blockIdx.x * 4 + (threadIdx.x >> 6);
  if (e >= E) return;
  int d = threadIdx.x & 63;
  int sn = src[e], dn = dst[e];
  float w0 = a_ws[e * 4 + 0] / asum[dn * 4 + 0];
  float w1 = a_ws[e * 4 + 1] / asum[dn * 4 + 1];
  float w2 = a_ws[e * 4 + 2] / asum[dn * 4 + 2];
  float w3 = a_ws[e * 4 + 3] / asum[dn * 4 + 3];
  const ushort* hqp = hq + (size_t)sn * 256;
  float y = w0 * bf2f(hqp[d]) + w1 * bf2f(hqp[64 + d]) +
            w2 * bf2f(hqp[128 + d]) + w3 * bf2f(hqp[192 + d]);
  atomicAdd(&agg[(size_t)dn * 64 + d], y);
}

// ---------------- K4: out0 = hE + agg + bp_node ----------------
__global__ void k4(const float* __restrict__ hE, const float* __restrict__ agg,
                   const float* __restrict__ bpn, float* __restrict__ out0,
                   int ND) {
  int i = blockIdx.x * 256 + threadIdx.x;
  if (i < ND) out0[i] = hE[i] + agg[i] + bpn[i & 63];
}

extern "C" void kernel_launch(void* const* d_in, const int* in_sizes, int n_in,
                              void* d_out, int out_size, void* d_ws, size_t ws_size,
                              hipStream_t stream) {
  const float* h_E    = (const float*)d_in[0];
  const float* h_H    = (const float*)d_in[1];
  const int*   src    = (const int*)d_in[2];
  const int*   dst    = (const int*)d_in[3];
  const float* W_node = (const float*)d_in[4];
  const float* b_node = (const float*)d_in[5];
  const float* W_ni   = (const float*)d_in[6];
  const float* W_nj   = (const float*)d_in[7];
  const float* W_fij  = (const float*)d_in[8];
  const float* attn   = (const float*)d_in[9];
  const float* Wp_node= (const float*)d_in[10];
  const float* bp_node= (const float*)d_in[11];
  const float* Wp_edge= (const float*)d_in[12];
  const float* bp_edge= (const float*)d_in[13];

  const int n = in_sizes[0] / 64;   // 50000 nodes
  const int e = in_sizes[1] / 64;   // 800000 edges

  // workspace layout
  ushort* ws_hEbf = (ushort*)d_ws;                      // n*64 bf16
  ushort* ws_hq   = ws_hEbf + (size_t)n * 64;           // n*256 bf16
  float*  ws_e    = (float*)(ws_hq + (size_t)n * 256);  // e*4
  float*  ws_a    = ws_e + (size_t)e * 4;               // e*4
  float*  ws_emax = ws_a + (size_t)e * 4;               // n*4
  float*  ws_asum = ws_emax + (size_t)n * 4;            // n*4
  float*  ws_agg  = ws_asum + (size_t)n * 4;            // n*64
  ushort* ws_Wcat = (ushort*)(ws_agg + (size_t)n * 64); // 256*192 bf16
  ushort* ws_WpeT = ws_Wcat + 49152;                    // 64*256 bf16

  float* out0 = (float*)d_out;               // (n,64)
  float* out1 = out0 + (size_t)n * 64;       // (e,64)

  {
    int total = n * 64;
    k_init<<<(total + 255) / 256, 256, 0, stream>>>(ws_emax, ws_asum, ws_agg, n);
  }
  k_prep<<<192, 256, 0, stream>>>(W_fij, W_ni, W_nj, Wp_edge, ws_Wcat, ws_WpeT);
  {
    int blocks = (n + 31) / 32;
    k_node<<<blocks, 256, 0, stream>>>(h_E, W_node, b_node, Wp_node,
                                       ws_hEbf, ws_hq, n);
  }
  {
    int ntiles = e / 32;  // E=800000 divisible by 32
    k_edge<<<512, 256, 0, stream>>>(h_H, src, dst, ws_Wcat, attn, ws_WpeT,
                                    bp_edge, ws_hEbf, ws_e, ws_emax, out1,
                                    ntiles);
  }
  {
    int total = e * 4;
    k3a<<<(total + 255) / 256, 256, 0, stream>>>(ws_e, dst, ws_emax, ws_a,
                                                 ws_asum, total);
  }
  {
    int blocks = (e + 3) / 4;
    k3b<<<blocks, 256, 0, stream>>>(ws_a, ws_asum, src, dst, ws_hq, ws_agg, e);
  }
  {
    int total = n * 64;
    k4<<<(total + 255) / 256, 256, 0, stream>>>(h_E, ws_agg, bp_node, out0,
                                                total);
  }
}